// Round 8
// baseline (1447.022 us; speedup 1.0000x reference)
//
#include <hip/hip_runtime.h>

#define N_NODES 50000
#define N_EDGES 800000
#define DIM 128
#define NB2 782         // buckets of 64 dst nodes
#define CAP2 1408       // padded capacity per bucket (mean 1023, +12 sigma)
#define NCH 7           // src chunks of 8192 nodes (2MB of Hs each)
#define BIN_CHUNK 4096
#define BIN_BLOCKS 196

typedef unsigned int uint;
typedef unsigned short ushort;
typedef __attribute__((ext_vector_type(8))) __bf16 bf16x8;
typedef __attribute__((ext_vector_type(4))) float f32x4;

// ---- bf16 pack/unpack helpers (round-to-nearest-even) ----
__device__ __forceinline__ uint f2bf(float f) {
    uint u = __float_as_uint(f);
    return (u + 0x7FFFu + ((u >> 16) & 1u)) >> 16;
}
__device__ __forceinline__ float2 bf2f2(uint u) {
    return make_float2(__uint_as_float(u << 16), __uint_as_float(u & 0xFFFF0000u));
}

// ---------------- prep: W^T bf16 pre-pack + bucket cursor init ----------------

__global__ __launch_bounds__(256) void prep_kernel(const float* __restrict__ W1,
                                                   const float* __restrict__ W2,
                                                   uint* __restrict__ Wt1,
                                                   uint* __restrict__ Wt2,
                                                   int* __restrict__ bincursor) {
    int idx = blockIdx.x * 256 + threadIdx.x;  // 0..17407
    if (idx < 16384) {
        const float* W = (idx < 8192) ? W1 : W2;
        uint* Wt = (idx < 8192) ? Wt1 : Wt2;
        int i = idx & 8191;
        int n = i >> 6, k2 = i & 63;
        uint lo = f2bf(W[(2 * k2) * DIM + n]);
        uint hi = f2bf(W[(2 * k2 + 1) * DIM + n]);
        Wt[i] = lo | (hi << 16);
    } else {
        int b = idx - 16384;
        if (b < NB2) bincursor[b] = b * CAP2;
    }
}

// ---------------- BIN: scatter edges into 782 dst-buckets (packed uint) ----------------
// pack = (src << 6) | (dst & 63)

__global__ __launch_bounds__(256) void bin_kernel(const int* __restrict__ ei,
                                                  int* __restrict__ bincursor,
                                                  uint* __restrict__ pairs) {
    __shared__ int lh[NB2];
    __shared__ int lbase[NB2];
    int t = threadIdx.x;
    int eb = blockIdx.x * BIN_CHUNK;

    for (int b = t; b < NB2; b += 256) lh[b] = 0;
    __syncthreads();

    int s_reg[16], d_reg[16];
#pragma unroll
    for (int i = 0; i < 16; ++i) {
        int e = eb + i * 256 + t;
        if (e < N_EDGES) {
            s_reg[i] = ei[e];
            d_reg[i] = ei[N_EDGES + e];
            atomicAdd(&lh[d_reg[i] >> 6], 1);
        } else {
            d_reg[i] = -1;
        }
    }
    __syncthreads();

    for (int b = t; b < NB2; b += 256) {
        int c = lh[b];
        lbase[b] = c ? atomicAdd(&bincursor[b], c) : 0;
    }
    __syncthreads();
    for (int b = t; b < NB2; b += 256) lh[b] = 0;
    __syncthreads();

#pragma unroll
    for (int i = 0; i < 16; ++i) {
        int d = d_reg[i];
        if (d >= 0) {
            int bin = d >> 6;
            int r = atomicAdd(&lh[bin], 1);
            pairs[lbase[bin] + r] = ((uint)s_reg[i] << 6) | (uint)(d & 63);
        }
    }
}

// ---------------- FILL3: per-bucket dinv + src-chunk counting sort ----------------

__global__ __launch_bounds__(256) void fill3_kernel(const uint* __restrict__ pairs,
                                                    const int* __restrict__ bincursor,
                                                    uint* __restrict__ pairs2,
                                                    float* __restrict__ dinv) {
    __shared__ int deg[64];
    __shared__ int ccnt[NCH];
    __shared__ int ccur[NCH];
    int t = threadIdx.x;
    int blk = blockIdx.x;
    int bs = blk * CAP2;
    int be = bincursor[blk];

    if (t < 64) deg[t] = 0;
    if (t < NCH) ccnt[t] = 0;
    __syncthreads();

    for (int p = bs + t; p < be; p += 256) {
        uint pr = pairs[p];
        atomicAdd(&deg[pr & 63u], 1);
        atomicAdd(&ccnt[pr >> 19], 1);  // chunk = src >> 13
    }
    __syncthreads();

    if (t == 0) {
        int s = 0;
#pragma unroll
        for (int i = 0; i < NCH; ++i) {
            ccur[i] = s;
            s += ccnt[i];
        }
    }
    __syncthreads();

    if (t < 64) {
        int node = blk * 64 + t;
        if (node < N_NODES) dinv[node] = rsqrtf((float)deg[t] + 1.0f);
    }

    for (int p = bs + t; p < be; p += 256) {
        uint pr = pairs[p];
        int r = atomicAdd(&ccur[pr >> 19], 1);
        pairs2[bs + r] = pr;
    }
}

// ---------------- MFMA GEMM: Hs = bf16( (X @ W) * dinv[row] ) ----------------

template <bool ABF>
__global__ __launch_bounds__(256) void mgemm_kernel(const void* __restrict__ Xv,
                                                    const uint* __restrict__ Wt,  // [128][64] uint
                                                    const float* __restrict__ dinv,
                                                    uint* __restrict__ Hs) {      // [M][64] uint
    int t = threadIdx.x;
    int wv = t >> 6;
    int l = t & 63;
    int col = l & 15;
    int g = l >> 4;
    int r0 = blockIdx.x * 64 + wv * 16;

    int ar = r0 + col;
    if (ar > N_NODES - 1) ar = N_NODES - 1;  // clamp (stores are guarded)

    bf16x8 a[4];
    if (ABF) {
        const uint4* Xr = (const uint4*)((const uint*)Xv + (size_t)ar * 64);
#pragma unroll
        for (int kk = 0; kk < 4; ++kk) a[kk] = __builtin_bit_cast(bf16x8, Xr[kk * 4 + g]);
    } else {
        const float4* Xr = (const float4*)((const float*)Xv + (size_t)ar * DIM);
#pragma unroll
        for (int kk = 0; kk < 4; ++kk) {
            float4 x0 = Xr[kk * 8 + g * 2];
            float4 x1 = Xr[kk * 8 + g * 2 + 1];
            uint4 p;
            p.x = f2bf(x0.x) | (f2bf(x0.y) << 16);
            p.y = f2bf(x0.z) | (f2bf(x0.w) << 16);
            p.z = f2bf(x1.x) | (f2bf(x1.y) << 16);
            p.w = f2bf(x1.z) | (f2bf(x1.w) << 16);
            a[kk] = __builtin_bit_cast(bf16x8, p);
        }
    }

    const uint4* Wr = (const uint4*)Wt;  // [128 rows][16 uint4]
    f32x4 acc[8];
#pragma unroll
    for (int n = 0; n < 8; ++n) acc[n] = (f32x4){0.f, 0.f, 0.f, 0.f};

#pragma unroll
    for (int n = 0; n < 8; ++n) {
        const uint4* wrow = Wr + (size_t)(n * 16 + col) * 16;
#pragma unroll
        for (int kk = 0; kk < 4; ++kk) {
            bf16x8 b = __builtin_bit_cast(bf16x8, wrow[kk * 4 + g]);
            acc[n] = __builtin_amdgcn_mfma_f32_16x16x32_bf16(a[kk], b, acc[n], 0, 0, 0);
        }
    }

#pragma unroll
    for (int j = 0; j < 4; ++j) {
        int row = r0 + g * 4 + j;
        if (row < N_NODES) {
            float di = dinv[row];
            ushort* hrow = (ushort*)(Hs + (size_t)row * 64);
#pragma unroll
            for (int n = 0; n < 8; ++n) {
                hrow[n * 16 + col] = (ushort)f2bf(acc[n][j] * di);
            }
        }
    }
}

// ---------------- agg3: edge-parallel, LDS accumulator per 64-node bucket ----------------
// acc layout: acc[d][129] with element j at phi(j) = (j&3)*32 + (j>>2)
// 32 lanes/edge; lane li loads uint2 (elements 4li..4li+3) -> ds_add banks (d+li)%32: conflict-free

template <bool RES, bool OBF>
__global__ __launch_bounds__(256) void agg3_kernel(const uint* __restrict__ pairs2,
                                                   const int* __restrict__ bincursor,
                                                   const uint* __restrict__ Hs,
                                                   const float* __restrict__ dinv,
                                                   const float* __restrict__ b,
                                                   const float* __restrict__ resid,
                                                   void* __restrict__ outv) {
    __shared__ float acc[64 * 129];  // 33 KB
    int t = threadIdx.x;
    int blk = blockIdx.x;
    int bs = blk * CAP2;
    int n_e = bincursor[blk] - bs;

    // zero acc (8256 floats = 2064 float4)
    float4* a4 = (float4*)acc;
    for (int i = t; i < 2064; i += 256) a4[i] = make_float4(0.f, 0.f, 0.f, 0.f);
    __syncthreads();

    int grp = t >> 5;  // 8 edge slots per iteration
    int li = t & 31;

    const int D = 8;  // software pipeline depth
    uint pr_[D];
    uint2 vr_[D];

    int it_total = (n_e + 7) >> 3;

#pragma unroll
    for (int i = 0; i < D; ++i) {
        int idx = i * 8 + grp;
        uint p = 0xFFFFFFFFu;
        uint2 v = make_uint2(0u, 0u);
        if (idx < n_e) {
            p = pairs2[bs + idx];
            v = *(const uint2*)(Hs + (size_t)(p >> 6) * 64 + 2 * li);
        }
        pr_[i] = p;
        vr_[i] = v;
    }

    for (int it0 = 0; it0 < it_total; it0 += D) {
#pragma unroll
        for (int i = 0; i < D; ++i) {
            uint p = pr_[i];
            uint2 v = vr_[i];
            if (p != 0xFFFFFFFFu) {
                float* ar = acc + (p & 63u) * 129;
                float2 w0 = bf2f2(v.x), w1 = bf2f2(v.y);
                atomicAdd(&ar[li], w0.x);
                atomicAdd(&ar[32 + li], w0.y);
                atomicAdd(&ar[64 + li], w1.x);
                atomicAdd(&ar[96 + li], w1.y);
            }
            int idx = (it0 + D + i) * 8 + grp;
            uint pn = 0xFFFFFFFFu;
            uint2 vn = make_uint2(0u, 0u);
            if (idx < n_e) {
                pn = pairs2[bs + idx];
                vn = *(const uint2*)(Hs + (size_t)(pn >> 6) * 64 + 2 * li);
            }
            pr_[i] = pn;
            vr_[i] = vn;
        }
    }
    __syncthreads();

    // writeout: thread -> (row r = t&63, phi-chunk c = t>>6 covering elements j = c*32..c*32+31)
    int r = t & 63;
    int c = t >> 6;
    int node = blk * 64 + r;
    if (node >= N_NODES) return;

    float di = dinv[node];
    const uint4* S4 = (const uint4*)(Hs + (size_t)node * 64 + c * 16);
    const float* ar = acc + r * 129;
    const float4* B4 = (const float4*)(b + c * 32);
    const float4* R4 = RES ? (const float4*)(resid + (size_t)node * DIM + c * 32) : nullptr;

#pragma unroll
    for (int q = 0; q < 4; ++q) {  // 8 elements per q: j = c*32 + q*8 + mm
        uint4 su = S4[q];
        float2 s0 = bf2f2(su.x), s1 = bf2f2(su.y), s2 = bf2f2(su.z), s3 = bf2f2(su.w);
        float o[8];
        o[0] = s0.x; o[1] = s0.y; o[2] = s1.x; o[3] = s1.y;
        o[4] = s2.x; o[5] = s2.y; o[6] = s3.x; o[7] = s3.y;
#pragma unroll
        for (int mm = 0; mm < 8; ++mm) {
            // m = q*8+mm ; acc index = (m&3)*32 + c*8 + (m>>2)
            float a = ar[((mm & 3) * 32) + c * 8 + q * 2 + (mm >> 2)];
            o[mm] = (o[mm] + a) * di;
        }
        float4 bb0 = B4[q * 2], bb1 = B4[q * 2 + 1];
        o[0] += bb0.x; o[1] += bb0.y; o[2] += bb0.z; o[3] += bb0.w;
        o[4] += bb1.x; o[5] += bb1.y; o[6] += bb1.z; o[7] += bb1.w;
        if (OBF) {
            uint4 u;
            u.x = f2bf(fmaxf(o[0], 0.f)) | (f2bf(fmaxf(o[1], 0.f)) << 16);
            u.y = f2bf(fmaxf(o[2], 0.f)) | (f2bf(fmaxf(o[3], 0.f)) << 16);
            u.z = f2bf(fmaxf(o[4], 0.f)) | (f2bf(fmaxf(o[5], 0.f)) << 16);
            u.w = f2bf(fmaxf(o[6], 0.f)) | (f2bf(fmaxf(o[7], 0.f)) << 16);
            ((uint4*)((uint*)outv + (size_t)node * 64 + c * 16))[q] = u;
        } else {
            if (RES) {
                float4 x0 = R4[q * 2], x1 = R4[q * 2 + 1];
                o[0] += x0.x; o[1] += x0.y; o[2] += x0.z; o[3] += x0.w;
                o[4] += x1.x; o[5] += x1.y; o[6] += x1.z; o[7] += x1.w;
            }
            float4* O4 = (float4*)((float*)outv + (size_t)node * DIM + c * 32);
            O4[q * 2] = make_float4(fmaxf(o[0], 0.f), fmaxf(o[1], 0.f), fmaxf(o[2], 0.f),
                                    fmaxf(o[3], 0.f));
            O4[q * 2 + 1] = make_float4(fmaxf(o[4], 0.f), fmaxf(o[5], 0.f), fmaxf(o[6], 0.f),
                                        fmaxf(o[7], 0.f));
        }
    }
}

// ---------------- launch ----------------

extern "C" void kernel_launch(void* const* d_in, const int* in_sizes, int n_in,
                              void* d_out, int out_size, void* d_ws, size_t ws_size,
                              hipStream_t stream) {
    const float* x = (const float*)d_in[0];
    const int* edge_index = (const int*)d_in[1];
    const float* W1 = (const float*)d_in[2];
    const float* b1 = (const float*)d_in[3];
    const float* W2 = (const float*)d_in[4];
    const float* b2 = (const float*)d_in[5];
    float* out = (float*)d_out;

    char* ws = (char*)d_ws;
    int*   bincursor = (int*)(ws + 0);              // 3.1 KB
    float* dinv      = (float*)(ws + (64 << 10));   // 200 KB
    uint*  Wt1       = (uint*)(ws + (320 << 10));   // 32 KB
    uint*  Wt2       = (uint*)(ws + (384 << 10));   // 32 KB
    uint*  pairs     = (uint*)(ws + (1 << 20));     // 4.4 MB (padded)
    uint*  pairs2    = (uint*)(ws + (6 << 20));     // 4.4 MB (padded, chunk-sorted)
    uint*  Hs        = (uint*)(ws + (11 << 20));    // 12.8 MB (bf16 packed)
    uint*  out1b     = (uint*)(ws + (24 << 20));    // 12.8 MB (bf16 packed)

    // ---- prep (W^T pack + cursor init) + bucketed edge lists + chunk sort + dinv
    prep_kernel<<<68, 256, 0, stream>>>(W1, W2, Wt1, Wt2, bincursor);
    bin_kernel<<<BIN_BLOCKS, 256, 0, stream>>>(edge_index, bincursor, pairs);
    fill3_kernel<<<NB2, 256, 0, stream>>>(pairs, bincursor, pairs2, dinv);

    const int gemm_grid = (N_NODES + 63) / 64;

    // ---- conv1: Hs = bf16((x@W1)*dinv) ; out1b = bf16(relu(agg + b1))
    mgemm_kernel<false><<<gemm_grid, 256, 0, stream>>>(x, Wt1, dinv, Hs);
    agg3_kernel<false, true><<<NB2, 256, 0, stream>>>(pairs2, bincursor, Hs, dinv, b1, nullptr,
                                                      out1b);

    // ---- conv2: Hs = bf16((out1b@W2)*dinv) ; out = relu(agg + b2 + x) -> d_out
    mgemm_kernel<true><<<gemm_grid, 256, 0, stream>>>(out1b, Wt2, dinv, Hs);
    agg3_kernel<true, false><<<NB2, 256, 0, stream>>>(pairs2, bincursor, Hs, dinv, b2, x, out);
}

// Round 9
// 139.250 us; speedup vs baseline: 10.3915x; 10.3915x over previous
//
#include <hip/hip_runtime.h>

#define N_NODES 50000
#define N_EDGES 800000
#define DIM 128
#define NB 391          // buckets of 128 dst nodes
#define CAP 2560        // padded capacity per bucket (mean 2048, +11 sigma)
#define NCH 7           // src chunks of 8192 nodes (2 MB of Hs each)
#define BIN_CHUNK 4096
#define BIN_BLOCKS 196

typedef unsigned int uint;
typedef unsigned short ushort;
typedef __attribute__((ext_vector_type(8))) __bf16 bf16x8;
typedef __attribute__((ext_vector_type(4))) float f32x4;

// ---- bf16 pack/unpack helpers (round-to-nearest-even) ----
__device__ __forceinline__ uint f2bf(float f) {
    uint u = __float_as_uint(f);
    return (u + 0x7FFFu + ((u >> 16) & 1u)) >> 16;
}
__device__ __forceinline__ float2 bf2f2(uint u) {
    return make_float2(__uint_as_float(u << 16), __uint_as_float(u & 0xFFFF0000u));
}

// ---------------- prep: W^T bf16 pre-pack + bucket cursor init ----------------

__global__ __launch_bounds__(256) void prep_kernel(const float* __restrict__ W1,
                                                   const float* __restrict__ W2,
                                                   uint* __restrict__ Wt1,
                                                   uint* __restrict__ Wt2,
                                                   int* __restrict__ bincursor) {
    int idx = blockIdx.x * 256 + threadIdx.x;
    if (idx < 16384) {
        const float* W = (idx < 8192) ? W1 : W2;
        uint* Wt = (idx < 8192) ? Wt1 : Wt2;
        int i = idx & 8191;
        int n = i >> 6, k2 = i & 63;
        uint lo = f2bf(W[(2 * k2) * DIM + n]);
        uint hi = f2bf(W[(2 * k2 + 1) * DIM + n]);
        Wt[i] = lo | (hi << 16);
    } else {
        int b = idx - 16384;
        if (b < NB) bincursor[b] = b * CAP;
    }
}

// ---------------- BIN: scatter edges into 391 dst-buckets (packed uint) ----------------
// pack = (src << 7) | (dst & 127)

__global__ __launch_bounds__(256) void bin_kernel(const int* __restrict__ ei,
                                                  int* __restrict__ bincursor,
                                                  uint* __restrict__ pairs) {
    __shared__ int lh[NB];
    __shared__ int lbase[NB];
    int t = threadIdx.x;
    int eb = blockIdx.x * BIN_CHUNK;

    for (int b = t; b < NB; b += 256) lh[b] = 0;
    __syncthreads();

    int s_reg[16], d_reg[16];
#pragma unroll
    for (int i = 0; i < 16; ++i) {
        int e = eb + i * 256 + t;
        if (e < N_EDGES) {
            s_reg[i] = ei[e];
            d_reg[i] = ei[N_EDGES + e];
            atomicAdd(&lh[d_reg[i] >> 7], 1);
        } else {
            d_reg[i] = -1;
        }
    }
    __syncthreads();

    for (int b = t; b < NB; b += 256) {
        int c = lh[b];
        lbase[b] = c ? atomicAdd(&bincursor[b], c) : 0;
    }
    __syncthreads();
    for (int b = t; b < NB; b += 256) lh[b] = 0;
    __syncthreads();

#pragma unroll
    for (int i = 0; i < 16; ++i) {
        int d = d_reg[i];
        if (d >= 0) {
            int bin = d >> 7;
            int r = atomicAdd(&lh[bin], 1);
            pairs[lbase[bin] + r] = ((uint)s_reg[i] << 7) | (uint)(d & 127);
        }
    }
}

// ---------------- FILL2v2: per-bucket CSR build, chunk-sorted per node ----------------
// csr order within node: grouped by src chunk (src>>13) -> temporal L2 locality in agg

__global__ __launch_bounds__(256) void fill2_kernel(const uint* __restrict__ pairs,
                                                    const int* __restrict__ bincursor,
                                                    int* __restrict__ rowbeg,
                                                    int* __restrict__ rowend,
                                                    float* __restrict__ dinv,
                                                    int* __restrict__ csr_src) {
    __shared__ int cnt[128 * 8];  // [node][chunk], chunk < NCH
    __shared__ int nsum[128];
    __shared__ int nbase[128];
    int t = threadIdx.x;
    int blk = blockIdx.x;
    int bs = blk * CAP;
    int be = bincursor[blk];

    for (int i = t; i < 128 * 8; i += 256) cnt[i] = 0;
    __syncthreads();

    for (int p = bs + t; p < be; p += 256) {
        uint pr = pairs[p];
        atomicAdd(&cnt[(pr & 127u) * 8 + (pr >> 20)], 1);
    }
    __syncthreads();

    if (t < 128) {
        int s = 0;
#pragma unroll
        for (int c = 0; c < NCH; ++c) s += cnt[t * 8 + c];
        nsum[t] = s;
        nbase[t] = s;
    }
    __syncthreads();
    // inclusive scan over nbase
#pragma unroll
    for (int off = 1; off < 128; off <<= 1) {
        int v = (t < 128 && t >= off) ? nbase[t - off] : 0;
        __syncthreads();
        if (t < 128) nbase[t] += v;
        __syncthreads();
    }

    if (t < 128) {
        int ex = nbase[t] - nsum[t];  // exclusive node base
        int node = blk * 128 + t;
        if (node < N_NODES) {
            rowbeg[node] = bs + ex;
            rowend[node] = bs + nbase[t];
            dinv[node] = rsqrtf((float)nsum[t] + 1.0f);
        }
        // turn cnt[t][*] into running write cursors (chunk-major within node)
        int run = ex;
#pragma unroll
        for (int c = 0; c < NCH; ++c) {
            int v = cnt[t * 8 + c];
            cnt[t * 8 + c] = run;
            run += v;
        }
    }
    __syncthreads();

    for (int p = bs + t; p < be; p += 256) {
        uint pr = pairs[p];
        int r = atomicAdd(&cnt[(pr & 127u) * 8 + (pr >> 20)], 1);
        csr_src[bs + r] = (int)(pr >> 7);
    }
}

// ---------------- MFMA GEMM: Hs = bf16( (X @ W) * dinv[row] ) ----------------

template <bool ABF>
__global__ __launch_bounds__(256) void mgemm_kernel(const void* __restrict__ Xv,
                                                    const uint* __restrict__ Wt,  // [128][64] uint
                                                    const float* __restrict__ dinv,
                                                    uint* __restrict__ Hs) {      // [M][64] uint
    int t = threadIdx.x;
    int wv = t >> 6;
    int l = t & 63;
    int col = l & 15;
    int g = l >> 4;
    int r0 = blockIdx.x * 64 + wv * 16;

    int ar = r0 + col;
    if (ar > N_NODES - 1) ar = N_NODES - 1;  // clamp (stores are guarded)

    bf16x8 a[4];
    if (ABF) {
        const uint4* Xr = (const uint4*)((const uint*)Xv + (size_t)ar * 64);
#pragma unroll
        for (int kk = 0; kk < 4; ++kk) a[kk] = __builtin_bit_cast(bf16x8, Xr[kk * 4 + g]);
    } else {
        const float4* Xr = (const float4*)((const float*)Xv + (size_t)ar * DIM);
#pragma unroll
        for (int kk = 0; kk < 4; ++kk) {
            float4 x0 = Xr[kk * 8 + g * 2];
            float4 x1 = Xr[kk * 8 + g * 2 + 1];
            uint4 p;
            p.x = f2bf(x0.x) | (f2bf(x0.y) << 16);
            p.y = f2bf(x0.z) | (f2bf(x0.w) << 16);
            p.z = f2bf(x1.x) | (f2bf(x1.y) << 16);
            p.w = f2bf(x1.z) | (f2bf(x1.w) << 16);
            a[kk] = __builtin_bit_cast(bf16x8, p);
        }
    }

    const uint4* Wr = (const uint4*)Wt;  // [128 rows][16 uint4]
    f32x4 acc[8];
#pragma unroll
    for (int n = 0; n < 8; ++n) acc[n] = (f32x4){0.f, 0.f, 0.f, 0.f};

#pragma unroll
    for (int n = 0; n < 8; ++n) {
        const uint4* wrow = Wr + (size_t)(n * 16 + col) * 16;
#pragma unroll
        for (int kk = 0; kk < 4; ++kk) {
            bf16x8 b = __builtin_bit_cast(bf16x8, wrow[kk * 4 + g]);
            acc[n] = __builtin_amdgcn_mfma_f32_16x16x32_bf16(a[kk], b, acc[n], 0, 0, 0);
        }
    }

#pragma unroll
    for (int j = 0; j < 4; ++j) {
        int row = r0 + g * 4 + j;
        if (row < N_NODES) {
            float di = dinv[row];
            ushort* hrow = (ushort*)(Hs + (size_t)row * 64);
#pragma unroll
            for (int n = 0; n < 8; ++n) {
                hrow[n * 16 + col] = (ushort)f2bf(acc[n][j] * di);
            }
        }
    }
}

// ---------------- aggregation: 4 nodes/wave, 16 lanes/node, uint4/lane, unroll-4 ----------------

template <bool RES, bool OBF>
__global__ __launch_bounds__(256) void agg_kernel(const int* __restrict__ rowbeg,
                                                  const int* __restrict__ rowend,
                                                  const int* __restrict__ csr_src,
                                                  const uint* __restrict__ Hs,
                                                  const float* __restrict__ dinv,
                                                  const float* __restrict__ b,
                                                  const float* __restrict__ resid,
                                                  void* __restrict__ outv) {
    int wave = (int)((blockIdx.x * (size_t)blockDim.x + threadIdx.x) >> 6);
    int lane = threadIdx.x & 63;
    int grp = lane >> 4;
    int li = lane & 15;
    int node = wave * 4 + grp;  // 50000 = 12500 waves * 4, exact

    int beg = rowbeg[node];
    int end = rowend[node];

    const uint4* H4 = (const uint4*)Hs;
    float a0, a1, a2, a3, a4, a5, a6, a7;
    {
        uint4 su = H4[(size_t)node * 16 + li];
        float2 v0 = bf2f2(su.x), v1 = bf2f2(su.y), v2 = bf2f2(su.z), v3 = bf2f2(su.w);
        a0 = v0.x; a1 = v0.y; a2 = v1.x; a3 = v1.y;
        a4 = v2.x; a5 = v2.y; a6 = v3.x; a7 = v3.y;
    }

#define ADD8(u)                                                                   \
    {                                                                             \
        float2 v0 = bf2f2(u.x), v1 = bf2f2(u.y), v2 = bf2f2(u.z), v3 = bf2f2(u.w);\
        a0 += v0.x; a1 += v0.y; a2 += v1.x; a3 += v1.y;                           \
        a4 += v2.x; a5 += v2.y; a6 += v3.x; a7 += v3.y;                           \
    }

    int e = beg;
    for (; e + 3 < end; e += 4) {
        int s0 = csr_src[e], s1 = csr_src[e + 1], s2 = csr_src[e + 2], s3 = csr_src[e + 3];
        uint4 u0 = H4[(size_t)s0 * 16 + li];
        uint4 u1 = H4[(size_t)s1 * 16 + li];
        uint4 u2 = H4[(size_t)s2 * 16 + li];
        uint4 u3 = H4[(size_t)s3 * 16 + li];
        ADD8(u0);
        ADD8(u1);
        ADD8(u2);
        ADD8(u3);
    }
    for (; e < end; ++e) {
        int s = csr_src[e];
        uint4 u = H4[(size_t)s * 16 + li];
        ADD8(u);
    }
#undef ADD8

    float di = dinv[node];
    const float4* B4 = (const float4*)b;
    float4 bb0 = B4[li * 2], bb1 = B4[li * 2 + 1];
    float r0 = a0 * di + bb0.x, r1 = a1 * di + bb0.y;
    float r2 = a2 * di + bb0.z, r3 = a3 * di + bb0.w;
    float r4 = a4 * di + bb1.x, r5 = a5 * di + bb1.y;
    float r6 = a6 * di + bb1.z, r7 = a7 * di + bb1.w;

    if (OBF) {
        uint4 o;
        o.x = f2bf(fmaxf(r0, 0.f)) | (f2bf(fmaxf(r1, 0.f)) << 16);
        o.y = f2bf(fmaxf(r2, 0.f)) | (f2bf(fmaxf(r3, 0.f)) << 16);
        o.z = f2bf(fmaxf(r4, 0.f)) | (f2bf(fmaxf(r5, 0.f)) << 16);
        o.w = f2bf(fmaxf(r6, 0.f)) | (f2bf(fmaxf(r7, 0.f)) << 16);
        ((uint4*)outv)[(size_t)node * 16 + li] = o;
    } else {
        if (RES) {
            const float4* R4 = (const float4*)(resid + (size_t)node * DIM);
            float4 x0 = R4[li * 2], x1 = R4[li * 2 + 1];
            r0 += x0.x; r1 += x0.y; r2 += x0.z; r3 += x0.w;
            r4 += x1.x; r5 += x1.y; r6 += x1.z; r7 += x1.w;
        }
        float4* O4 = (float4*)((float*)outv + (size_t)node * DIM);
        O4[li * 2] = make_float4(fmaxf(r0, 0.f), fmaxf(r1, 0.f), fmaxf(r2, 0.f), fmaxf(r3, 0.f));
        O4[li * 2 + 1] = make_float4(fmaxf(r4, 0.f), fmaxf(r5, 0.f), fmaxf(r6, 0.f), fmaxf(r7, 0.f));
    }
}

// ---------------- launch ----------------

extern "C" void kernel_launch(void* const* d_in, const int* in_sizes, int n_in,
                              void* d_out, int out_size, void* d_ws, size_t ws_size,
                              hipStream_t stream) {
    const float* x = (const float*)d_in[0];
    const int* edge_index = (const int*)d_in[1];
    const float* W1 = (const float*)d_in[2];
    const float* b1 = (const float*)d_in[3];
    const float* W2 = (const float*)d_in[4];
    const float* b2 = (const float*)d_in[5];
    float* out = (float*)d_out;

    char* ws = (char*)d_ws;
    int*   bincursor = (int*)(ws + 0);              // 1.6 KB
    float* dinv      = (float*)(ws + (64 << 10));   // 200 KB
    int*   rowbeg    = (int*)(ws + (320 << 10));    // 200 KB
    int*   rowend    = (int*)(ws + (576 << 10));    // 200 KB
    int*   csr_src   = (int*)(ws + (1 << 20));      // 4.0 MB (padded)
    uint*  pairs     = (uint*)(ws + (6 << 20));     // 4.0 MB (packed, padded)
    uint*  Hs        = (uint*)(ws + (11 << 20));    // 12.8 MB (bf16 packed)
    uint*  out1b     = (uint*)(ws + (24 << 20));    // 12.8 MB (bf16 packed)
    uint*  Wt1       = (uint*)(ws + (37 << 20));    // 32 KB
    uint*  Wt2       = (uint*)(ws + (37 << 20) + (64 << 10));  // 32 KB

    // ---- prep (W^T pack + cursor init) + CSR build (chunk-sorted)
    prep_kernel<<<66, 256, 0, stream>>>(W1, W2, Wt1, Wt2, bincursor);
    bin_kernel<<<BIN_BLOCKS, 256, 0, stream>>>(edge_index, bincursor, pairs);
    fill2_kernel<<<NB, 256, 0, stream>>>(pairs, bincursor, rowbeg, rowend, dinv, csr_src);

    const int gemm_grid = (N_NODES + 63) / 64;
    const int agg_grid = 3125;  // 50000 nodes / (4 nodes/wave * 4 waves/block)

    // ---- conv1: Hs = bf16((x@W1)*dinv) ; out1b = bf16(relu(agg + b1))
    mgemm_kernel<false><<<gemm_grid, 256, 0, stream>>>(x, Wt1, dinv, Hs);
    agg_kernel<false, true><<<agg_grid, 256, 0, stream>>>(rowbeg, rowend, csr_src, Hs, dinv, b1,
                                                          nullptr, out1b);

    // ---- conv2: Hs = bf16((out1b@W2)*dinv) ; out = relu(agg + b2 + x) -> d_out
    mgemm_kernel<true><<<gemm_grid, 256, 0, stream>>>(out1b, Wt2, dinv, Hs);
    agg_kernel<true, false><<<agg_grid, 256, 0, stream>>>(rowbeg, rowend, csr_src, Hs, dinv, b2,
                                                          x, out);
}